// Round 1
// baseline (127.154 us; speedup 1.0000x reference)
//
#include <hip/hip_runtime.h>

#define BB 4
#define TT 512
#define HH 512
#define UU 256

// 2*log2(e): e^{2x} = 2^{c*x}
__device__ __constant__ float kC2L2E = 2.8853900817779268f;
__device__ __constant__ float kL2E   = 1.4426950408889634f;

// ---------------- prep: w2[u] = -2*W[u], scal = {sum(W), b_alpha} ----------------
__global__ __launch_bounds__(256) void prep_kernel(const float* __restrict__ W,
                                                   const float* __restrict__ b_alpha,
                                                   float* __restrict__ w2,
                                                   float* __restrict__ scal)
{
    __shared__ float red[256];
    const int tid = threadIdx.x;
    const float w = W[tid];
    w2[tid] = -2.0f * w;
    red[tid] = w;
    __syncthreads();
    for (int off = 128; off > 0; off >>= 1) {
        if (tid < off) red[tid] += red[tid + off];
        __syncthreads();
    }
    if (tid == 0) { scal[0] = red[0]; scal[1] = b_alpha[0]; }
}

// ---------------- kernel 1: hq_s = c*(h@Wq + bq), hk_s = c*(h@Wk) ----------------
// M = B*T = 2048 rows, K = H = 512, N = 256 per weight (both fused: nt 0..3 -> Wq, 4..7 -> Wk)
__global__ __launch_bounds__(256) void qk_gemm(const float* __restrict__ h,
                                               const float* __restrict__ Wq,
                                               const float* __restrict__ Wk,
                                               const float* __restrict__ bq,
                                               float* __restrict__ hq_s,
                                               float* __restrict__ hk_s)
{
    __shared__ float As[16][68]; // [k][m], padded
    __shared__ float Bs[16][68]; // [k][n], padded
    const int tid = threadIdx.x;
    const int m0 = blockIdx.y * 64;
    const int nt = blockIdx.x;            // 0..7
    const bool isQ = nt < 4;
    const float* __restrict__ Wsrc = isQ ? Wq : Wk;
    const int n0 = (nt & 3) * 64;
    const int tx = tid & 15, ty = tid >> 4;
    const int lr = tid >> 2, lk = (tid & 3) * 4;   // A loader: row, k4
    const int bk = tid >> 4, bn = (tid & 15) * 4;  // B loader: k, n4

    float acc[4][4];
#pragma unroll
    for (int i = 0; i < 4; i++)
#pragma unroll
        for (int j = 0; j < 4; j++) acc[i][j] = 0.0f;

    for (int k0 = 0; k0 < HH; k0 += 16) {
        const float4 av = *(const float4*)(h + (size_t)(m0 + lr) * HH + k0 + lk);
        const float4 bv = *(const float4*)(Wsrc + (size_t)(k0 + bk) * UU + n0 + bn);
        __syncthreads();
        As[lk + 0][lr] = av.x; As[lk + 1][lr] = av.y;
        As[lk + 2][lr] = av.z; As[lk + 3][lr] = av.w;
        *(float4*)&Bs[bk][bn] = bv;
        __syncthreads();
#pragma unroll
        for (int kk = 0; kk < 16; kk++) {
            const float4 a = *(const float4*)&As[kk][ty * 4];
            const float4 b = *(const float4*)&Bs[kk][tx * 4];
            acc[0][0] = fmaf(a.x, b.x, acc[0][0]);
            acc[0][1] = fmaf(a.x, b.y, acc[0][1]);
            acc[0][2] = fmaf(a.x, b.z, acc[0][2]);
            acc[0][3] = fmaf(a.x, b.w, acc[0][3]);
            acc[1][0] = fmaf(a.y, b.x, acc[1][0]);
            acc[1][1] = fmaf(a.y, b.y, acc[1][1]);
            acc[1][2] = fmaf(a.y, b.z, acc[1][2]);
            acc[1][3] = fmaf(a.y, b.w, acc[1][3]);
            acc[2][0] = fmaf(a.z, b.x, acc[2][0]);
            acc[2][1] = fmaf(a.z, b.y, acc[2][1]);
            acc[2][2] = fmaf(a.z, b.z, acc[2][2]);
            acc[2][3] = fmaf(a.z, b.w, acc[2][3]);
            acc[3][0] = fmaf(a.w, b.x, acc[3][0]);
            acc[3][1] = fmaf(a.w, b.y, acc[3][1]);
            acc[3][2] = fmaf(a.w, b.z, acc[3][2]);
            acc[3][3] = fmaf(a.w, b.w, acc[3][3]);
        }
    }

    const float c = kC2L2E;
#pragma unroll
    for (int i = 0; i < 4; i++) {
        const int m = m0 + ty * 4 + i;
#pragma unroll
        for (int j = 0; j < 4; j++) {
            const int n = n0 + tx * 4 + j;
            const float v = acc[i][j];
            if (isQ) hq_s[(size_t)m * UU + n] = c * (v + bq[n]);
            else     hk_s[(size_t)m * UU + n] = c * v;
        }
    }
}

// ---------------- kernel 2a: scores + sigmoid + exp, per-(b,t) denom ----------------
// grid (sg=16, tg=8, b=4), block 256 (4 waves). lane = t within tg; wave owns 8 s.
__global__ __launch_bounds__(256) void score_kernel(const float* __restrict__ hq_s,
                                                    const float* __restrict__ hk_s,
                                                    const float* __restrict__ w2,
                                                    const float* __restrict__ scal,
                                                    float* __restrict__ E,
                                                    float* __restrict__ denom)
{
    const int b  = blockIdx.z;
    const int tg = blockIdx.y;
    const int sg = blockIdx.x;
    const int lane = threadIdx.x & 63;
    const int wv = __builtin_amdgcn_readfirstlane((int)(threadIdx.x >> 6));
    const int t  = tg * 64 + lane;
    const int s0 = sg * 32 + wv * 8;

    const float sumW    = scal[0];
    const float b_alpha = scal[1];
    const float* __restrict__ hq_row = hq_s + (size_t)(b * TT + t) * UU;

    float acc[8];
#pragma unroll
    for (int i = 0; i < 8; i++) acc[i] = 0.0f;

    for (int uc = 0; uc < UU; uc += 32) {
        float4 hr[8];
#pragma unroll
        for (int i = 0; i < 8; i++) hr[i] = *(const float4*)(hq_row + uc + i * 4);
        const float* __restrict__ w2c = w2 + uc;
#pragma unroll
        for (int si = 0; si < 8; ++si) {
            const float* __restrict__ hkr = hk_s + (size_t)(b * TT + s0 + si) * UU + uc;
#pragma unroll
            for (int u = 0; u < 32; ++u) {
                const float x = ((const float*)hr)[u] + hkr[u];     // c*(hq+hk+bq)
                const float e = __builtin_amdgcn_exp2f(x);          // e^{2x}
                const float r = __builtin_amdgcn_rcpf(1.0f + e);
                acc[si] = fmaf(w2c[u], r, acc[si]);                 // += -2W*r
            }
        }
    }

    float Ev[8];
    float part = 0.0f;
#pragma unroll
    for (int si = 0; si < 8; ++si) {
        const float z   = acc[si] + sumW + b_alpha;                         // score pre-sigmoid
        const float sgm = __builtin_amdgcn_rcpf(1.0f + __builtin_amdgcn_exp2f(-z * kL2E));
        const float e   = __builtin_amdgcn_exp2f(sgm * kL2E);               // exp(sigmoid)
        Ev[si] = e;
        part += e;
    }

    float* __restrict__ Erow = E + (size_t)(b * TT + t) * TT + s0;
    *(float4*)(Erow + 0) = make_float4(Ev[0], Ev[1], Ev[2], Ev[3]);
    *(float4*)(Erow + 4) = make_float4(Ev[4], Ev[5], Ev[6], Ev[7]);
    atomicAdd(&denom[b * TT + t], part);
}

// ---------------- kernel 2b: wsum[b,s] = (1/T) * sum_t E[b,t,s]/denom[b,t] ----------------
__global__ __launch_bounds__(256) void colsum_kernel(const float* __restrict__ E,
                                                     const float* __restrict__ denom,
                                                     float* __restrict__ wsum)
{
    const int b  = blockIdx.y;
    const int t0 = blockIdx.x * 32;
    const int s  = threadIdx.x;
    float a0 = 0.0f, a1 = 0.0f;
    for (int ti = 0; ti < 32; ++ti) {
        const int t = t0 + ti;
        const float rd = 1.0f / denom[b * TT + t];
        const float* __restrict__ Er = E + (size_t)(b * TT + t) * TT;
        a0 = fmaf(Er[s],       rd, a0);
        a1 = fmaf(Er[s + 256], rd, a1);
    }
    atomicAdd(&wsum[b * TT + s],       a0 * (1.0f / TT));
    atomicAdd(&wsum[b * TT + s + 256], a1 * (1.0f / TT));
}

// ---------------- kernel 3: out[b,:] = sum_s wsum[b,s] * h[b,s,:] ----------------
__global__ __launch_bounds__(512) void ctx_kernel(const float* __restrict__ h,
                                                  const float* __restrict__ wsum,
                                                  float* __restrict__ out)
{
    const int b  = blockIdx.y;
    const int s0 = blockIdx.x * 64;
    const int hd = threadIdx.x;
    float a = 0.0f;
    for (int si = 0; si < 64; ++si) {
        const int s = s0 + si;
        a = fmaf(wsum[b * TT + s], h[(size_t)(b * TT + s) * HH + hd], a);
    }
    atomicAdd(&out[b * HH + hd], a);
}

extern "C" void kernel_launch(void* const* d_in, const int* in_sizes, int n_in,
                              void* d_out, int out_size, void* d_ws, size_t ws_size,
                              hipStream_t stream)
{
    const float* h       = (const float*)d_in[0];
    const float* Wq      = (const float*)d_in[1];
    const float* Wk      = (const float*)d_in[2];
    const float* bq      = (const float*)d_in[3];
    const float* W       = (const float*)d_in[4];
    const float* b_alpha = (const float*)d_in[5];
    float* out = (float*)d_out;

    float* ws   = (float*)d_ws;
    float* hq_s = ws;                                 // B*T*U = 524288
    float* hk_s = hq_s + (size_t)BB * TT * UU;        // 524288
    float* E    = hk_s + (size_t)BB * TT * UU;        // B*T*T = 1048576
    float* denom= E + (size_t)BB * TT * TT;           // 2048
    float* wsum = denom + BB * TT;                    // 2048
    float* w2   = wsum + BB * TT;                     // 256
    float* scal = w2 + UU;                            // 2

    hipMemsetAsync(denom, 0, BB * TT * sizeof(float), stream);
    hipMemsetAsync(wsum,  0, BB * TT * sizeof(float), stream);
    hipMemsetAsync(d_out, 0, out_size * sizeof(float), stream);

    prep_kernel <<<1, 256, 0, stream>>>(W, b_alpha, w2, scal);
    qk_gemm     <<<dim3(8, 32), 256, 0, stream>>>(h, Wq, Wk, bq, hq_s, hk_s);
    score_kernel<<<dim3(16, 8, BB), 256, 0, stream>>>(hq_s, hk_s, w2, scal, E, denom);
    colsum_kernel<<<dim3(16, BB), 256, 0, stream>>>(E, denom, wsum);
    ctx_kernel  <<<dim3(8, BB), 512, 0, stream>>>(h, wsum, out);
}

// Round 2
// 102.728 us; speedup vs baseline: 1.2378x; 1.2378x over previous
//
#include <hip/hip_runtime.h>

#define BB 4
#define TT 512
#define HH 512
#define UU 256

// 2*log2(e): e^{2x} = 2^{c*x}
#define C2L2E 2.8853900817779268f
#define L2E   1.4426950408889634f

typedef __attribute__((ext_vector_type(8))) short bf16x8;
typedef __attribute__((ext_vector_type(4))) float f32x4;

static __device__ inline unsigned short f2bf(float x) {
    union { float f; unsigned u; } v; v.f = x;
    unsigned r = v.u + 0x7fff + ((v.u >> 16) & 1);   // RNE
    return (unsigned short)(r >> 16);
}

// ---------------- prep: w2/scal/cbq, zero denom/wsum/out, h->bf16, WcatT ----------------
__global__ __launch_bounds__(256) void prep_kernel(const float* __restrict__ h,
                                                   const float* __restrict__ Wq,
                                                   const float* __restrict__ Wk,
                                                   const float* __restrict__ bq,
                                                   const float* __restrict__ W,
                                                   const float* __restrict__ b_alpha,
                                                   unsigned short* __restrict__ hbf,
                                                   unsigned short* __restrict__ WcatT,
                                                   float* __restrict__ cbq,
                                                   float* __restrict__ w2,
                                                   float* __restrict__ scal,
                                                   float* __restrict__ denom,
                                                   float* __restrict__ wsum,
                                                   float* __restrict__ out)
{
    const int tid = threadIdx.x;
    const int gid = blockIdx.x * 256 + tid;
    const int nthr = gridDim.x * 256;

    if (blockIdx.x == 0) {
        __shared__ float red[256];
        const float w = W[tid];
        w2[tid] = -2.0f * w;
        red[tid] = w;
        cbq[tid] = C2L2E * bq[tid];
        __syncthreads();
        for (int off = 128; off > 0; off >>= 1) {
            if (tid < off) red[tid] += red[tid + off];
            __syncthreads();
        }
        if (tid == 0) { scal[0] = red[0]; scal[1] = b_alpha[0]; }
    }

    for (int i = gid; i < BB * TT; i += nthr) {
        denom[i] = 0.0f; wsum[i] = 0.0f; out[i] = 0.0f;
    }
    for (int i = gid; i < BB * TT * HH; i += nthr) {
        hbf[i] = f2bf(h[i]);
    }
    // WcatT[n][k] = bf16(c * W{q,k}[k][n]), n in [0,512), k in [0,512)
    for (int i = gid; i < 512 * 512; i += nthr) {
        const int n = i & 511, k = i >> 9;
        const float v = (n < 256) ? Wq[k * UU + n] : Wk[k * UU + (n - 256)];
        WcatT[(size_t)n * 512 + k] = f2bf(C2L2E * v);
    }
}

// ---------------- kernel 1: C[m][n] = hbf @ WcatT^T  (bf16 MFMA, fp32 out) ----------------
// M=2048, N=512 (cols 0..255 = c*hq, cols 256..511 = c*hk + c*bq), K=512.
// Each wave: 16x32 output (2 n-frags), fragments loaded straight from global.
__global__ __launch_bounds__(256) void qk_mfma(const unsigned short* __restrict__ hbf,
                                               const unsigned short* __restrict__ WcatT,
                                               const float* __restrict__ cbq,
                                               float* __restrict__ C)
{
    const int wave = (blockIdx.x * 256 + threadIdx.x) >> 6;   // 0..2047
    const int lane = threadIdx.x & 63;
    const int mt = wave >> 4;          // 0..127
    const int nt = wave & 15;          // 0..15
    const int m0 = mt * 16, n0 = nt * 32;
    const int lrow = lane & 15;
    const int kgrp = lane >> 4;        // 0..3

    f32x4 acc0 = {0.f, 0.f, 0.f, 0.f};
    f32x4 acc1 = {0.f, 0.f, 0.f, 0.f};
    const unsigned short* Arow = hbf   + (size_t)(m0 + lrow) * 512 + kgrp * 8;
    const unsigned short* B0   = WcatT + (size_t)(n0 + lrow) * 512 + kgrp * 8;
    const unsigned short* B1   = B0 + (size_t)16 * 512;

#pragma unroll
    for (int k0 = 0; k0 < 512; k0 += 32) {
        const bf16x8 a  = *(const bf16x8*)(Arow + k0);
        const bf16x8 b0 = *(const bf16x8*)(B0 + k0);
        const bf16x8 b1 = *(const bf16x8*)(B1 + k0);
        acc0 = __builtin_amdgcn_mfma_f32_16x16x32_bf16(a, b0, acc0, 0, 0, 0);
        acc1 = __builtin_amdgcn_mfma_f32_16x16x32_bf16(a, b1, acc1, 0, 0, 0);
    }

    const int n_0 = n0 + lrow;
    const int n_1 = n0 + 16 + lrow;
    const float bias0 = (n_0 >= 256) ? cbq[n_0 - 256] : 0.0f;
    const float bias1 = (n_1 >= 256) ? cbq[n_1 - 256] : 0.0f;
#pragma unroll
    for (int r = 0; r < 4; r++) {
        const int m = m0 + kgrp * 4 + r;
        C[(size_t)m * 512 + n_0] = acc0[r] + bias0;
        C[(size_t)m * 512 + n_1] = acc1[r] + bias1;
    }
}

// ---------------- kernel 2a: scores + sigmoid + exp, per-(b,t) denom ----------------
// grid (sg=32, tg=8, b=4), block 256 (4 waves). lane = t; wave owns 4 s.
__global__ __launch_bounds__(256) void score_kernel(const float* __restrict__ C,
                                                    const float* __restrict__ w2,
                                                    const float* __restrict__ scal,
                                                    float* __restrict__ E,
                                                    float* __restrict__ denom)
{
    const int b  = blockIdx.z;
    const int tg = blockIdx.y;
    const int sg = blockIdx.x;
    const int lane = threadIdx.x & 63;
    const int wv = __builtin_amdgcn_readfirstlane((int)(threadIdx.x >> 6));
    const int t  = tg * 64 + lane;
    const int s0 = sg * 16 + wv * 4;

    const float sumW    = scal[0];
    const float b_alpha = scal[1];
    const float* __restrict__ hq_row = C + (size_t)(b * TT + t) * 512;

    float acc[4] = {0.f, 0.f, 0.f, 0.f};

    for (int uc = 0; uc < UU; uc += 32) {
        float4 hr[8];
#pragma unroll
        for (int i = 0; i < 8; i++) hr[i] = *(const float4*)(hq_row + uc + i * 4);
        const float* __restrict__ w2c = w2 + uc;
#pragma unroll
        for (int si = 0; si < 4; ++si) {
            const float* __restrict__ hkr = C + (size_t)(b * TT + s0 + si) * 512 + 256 + uc;
#pragma unroll
            for (int u = 0; u < 32; ++u) {
                const float x = ((const float*)hr)[u] + hkr[u];     // c*(hq+hk+bq)
                const float e = __builtin_amdgcn_exp2f(x);          // e^{2x}
                const float r = __builtin_amdgcn_rcpf(1.0f + e);
                acc[si] = fmaf(w2c[u], r, acc[si]);                 // += -2W*r
            }
        }
    }

    float Ev[4];
    float part = 0.0f;
#pragma unroll
    for (int si = 0; si < 4; ++si) {
        const float z   = acc[si] + sumW + b_alpha;                       // pre-sigmoid
        const float sgm = __builtin_amdgcn_rcpf(1.0f + __builtin_amdgcn_exp2f(-z * L2E));
        const float e   = __builtin_amdgcn_exp2f(sgm * L2E);              // exp(sigmoid)
        Ev[si] = e;
        part += e;
    }

    float* __restrict__ Erow = E + (size_t)(b * TT + t) * TT + s0;
    *(float4*)Erow = make_float4(Ev[0], Ev[1], Ev[2], Ev[3]);
    atomicAdd(&denom[b * TT + t], part);
}

// ---------------- kernel 2b: wsum[b,s] = (1/T) * sum_t E[b,t,s]/denom[b,t] ----------------
__global__ __launch_bounds__(256) void colsum_kernel(const float* __restrict__ E,
                                                     const float* __restrict__ denom,
                                                     float* __restrict__ wsum)
{
    const int b  = blockIdx.y;
    const int t0 = blockIdx.x * 8;
    const int s  = threadIdx.x;
    float a0 = 0.0f, a1 = 0.0f;
#pragma unroll
    for (int ti = 0; ti < 8; ++ti) {
        const int t = t0 + ti;
        const float rd = 1.0f / denom[b * TT + t];
        const float* __restrict__ Er = E + (size_t)(b * TT + t) * TT;
        a0 = fmaf(Er[s],       rd, a0);
        a1 = fmaf(Er[s + 256], rd, a1);
    }
    atomicAdd(&wsum[b * TT + s],       a0 * (1.0f / TT));
    atomicAdd(&wsum[b * TT + s + 256], a1 * (1.0f / TT));
}

// ---------------- kernel 3: out[b,:] = sum_s wsum[b,s] * h[b,s,:] ----------------
__global__ __launch_bounds__(512) void ctx_kernel(const float* __restrict__ h,
                                                  const float* __restrict__ wsum,
                                                  float* __restrict__ out)
{
    const int b  = blockIdx.y;
    const int s0 = blockIdx.x * 32;
    const int hd = threadIdx.x;
    float a = 0.0f;
#pragma unroll
    for (int si = 0; si < 32; ++si) {
        const int s = s0 + si;
        a = fmaf(wsum[b * TT + s], h[(size_t)(b * TT + s) * HH + hd], a);
    }
    atomicAdd(&out[b * HH + hd], a);
}

extern "C" void kernel_launch(void* const* d_in, const int* in_sizes, int n_in,
                              void* d_out, int out_size, void* d_ws, size_t ws_size,
                              hipStream_t stream)
{
    const float* h       = (const float*)d_in[0];
    const float* Wq      = (const float*)d_in[1];
    const float* Wk      = (const float*)d_in[2];
    const float* bq      = (const float*)d_in[3];
    const float* W       = (const float*)d_in[4];
    const float* b_alpha = (const float*)d_in[5];
    float* out = (float*)d_out;

    float* ws    = (float*)d_ws;
    float* C     = ws;                                   // 2048*512 = 1,048,576 f32
    float* E     = C + (size_t)2048 * 512;               // 1,048,576 f32
    float* denom = E + (size_t)BB * TT * TT;             // 2048
    float* wsum  = denom + BB * TT;                      // 2048
    float* w2    = wsum + BB * TT;                       // 256
    float* scal  = w2 + UU;                              // 2
    float* cbq   = scal + 2;                             // 256

    // bf16 staging aliases E (E is only written by score_kernel, after qk_mfma)
    unsigned short* hbf   = (unsigned short*)E;          // 1,048,576 bf16 = 2 MB
    unsigned short* WcatT = hbf + (size_t)1048576;       // 262,144 bf16 = 512 KB

    prep_kernel  <<<64, 256, 0, stream>>>(h, Wq, Wk, bq, W, b_alpha,
                                          hbf, WcatT, cbq, w2, scal, denom, wsum, out);
    qk_mfma      <<<512, 256, 0, stream>>>(hbf, WcatT, cbq, C);
    score_kernel <<<dim3(32, 8, BB), 256, 0, stream>>>(C, w2, scal, E, denom);
    colsum_kernel<<<dim3(64, BB), 256, 0, stream>>>(E, denom, wsum);
    ctx_kernel   <<<dim3(16, BB), 512, 0, stream>>>(h, wsum, out);
}